// Round 8
// baseline (578.753 us; speedup 1.0000x reference)
//
#include <hip/hip_runtime.h>
#include <hip/hip_bf16.h>

// DomainSpecificHeads: out[b] = (hs[b] @ W_base + b_base) @ W_heads[idx[b]] + b_heads[idx[b]]
// B=8 S=512 D=1024 V=32000 ND=8 (slot ND = default head for out-of-range ids)

#define BCNT 8
#define SLEN 512
#define DDIM 1024
#define VDIM 32000
#define NDOM 8

typedef __attribute__((ext_vector_type(4))) float f32x4;
typedef __attribute__((ext_vector_type(8))) short bf16x8;

static __device__ __forceinline__ unsigned short f2bf(float f) {
    union { float f; unsigned int u; } x; x.f = f;
    unsigned int u = x.u;
    return (unsigned short)((u + 0x7FFFu + ((u >> 16) & 1u)) >> 16);  // RNE
}

// packed RNE f32x2 -> bf16x2 ; compiles to v_cvt_pk_bf16_f32
static __device__ __forceinline__ unsigned int pack2(float lo, float hi) {
    float2 t; t.x = lo; t.y = hi;
    union { __hip_bfloat162 h; unsigned int u; } c;
    c.h = __float22bfloat162_rn(t);
    return c.u;
}

#define SBAR()   __builtin_amdgcn_s_barrier()
#define SCHED0() __builtin_amdgcn_sched_barrier(0)

// ---------------- G1: hidden = hs @ W_base + b_base  (fp32 in, bf16 out) ----------------
// 128x128 tile, BK=64, 256 threads, 2x2 waves (validated round-1 structure).
__global__ __launch_bounds__(256)
void gemm1_k(const float* __restrict__ Af, const float* __restrict__ Bbase,
             const float* __restrict__ bias, __hip_bfloat16* __restrict__ Cb,
             int Mrows)
{
    __shared__ __align__(16) __hip_bfloat16 lds_a[128 * 64];
    __shared__ __align__(16) unsigned int   lds_b[32 * 128];

    const int tid  = threadIdx.x;
    const int lane = tid & 63;
    const int w    = tid >> 6;

    const int nwg = gridDim.x;
    const int bid = blockIdx.x;
    const int q   = nwg >> 3;
    const int sid = (bid & 7) * q + (bid >> 3);

    const int MT = Mrows >> 7;
    const int mt = sid % MT;
    const int nt = sid / MT;
    const int m0 = mt << 7;
    const int n0 = nt << 7;

    f32x4 acc[4][4];
    #pragma unroll
    for (int m = 0; m < 4; ++m)
        #pragma unroll
        for (int n = 0; n < 4; ++n)
            acc[m][n] = (f32x4)0.0f;

    const int wr = w >> 1, wc = w & 1;
    const int lr = lane & 15, lg = lane >> 4;

    for (int kt = 0; kt < DDIM / 64; ++kt) {
        const int kbase = kt * 64;

        #pragma unroll
        for (int t = 0; t < 8; ++t) {
            const int flat = (t * 256 + tid) * 4;
            const int row = flat >> 6, col = flat & 63;
            const float4 v = *(const float4*)(Af + (size_t)(m0 + row) * DDIM + kbase + col);
            uint2 pp;
            pp.x = pack2(v.x, v.y);
            pp.y = pack2(v.z, v.w);
            *(uint2*)(lds_a + flat) = pp;
        }

        #pragma unroll
        for (int t = 0; t < 4; ++t) {
            const int id = t * 256 + tid;
            const int kk = id >> 5;
            const int n  = (id & 31) << 2;
            const float* b0 = Bbase + (size_t)(kbase + 2 * kk) * DDIM + n0 + n;
            const float4 e = *(const float4*)b0;
            const float4 o = *(const float4*)(b0 + DDIM);
            uint4 pw;
            pw.x = pack2(e.x, o.x);
            pw.y = pack2(e.y, o.y);
            pw.z = pack2(e.z, o.z);
            pw.w = pack2(e.w, o.w);
            const int ns = n ^ ((kk & 4) << 2);
            *(uint4*)&lds_b[kk * 128 + ns] = pw;
        }

        __syncthreads();

        #pragma unroll
        for (int ks = 0; ks < 2; ++ks) {
            bf16x8 af[4], bfr[4];
            #pragma unroll
            for (int m = 0; m < 4; ++m) {
                const int row = wr * 64 + m * 16 + lr;
                const int k   = ks * 32 + lg * 8;
                af[m] = *(const bf16x8*)&lds_a[row * 64 + k];
            }
            #pragma unroll
            for (int n = 0; n < 4; ++n) {
                const int col = wc * 64 + n * 16 + lr;
                const int kkb = ks * 16 + lg * 4;
                union { unsigned int u[4]; bf16x8 v; } cvt;
                #pragma unroll
                for (int j = 0; j < 4; ++j) {
                    const int kk = kkb + j;
                    const int ns = col ^ ((kk & 4) << 2);
                    cvt.u[j] = lds_b[kk * 128 + ns];
                }
                bfr[n] = cvt.v;
            }
            #pragma unroll
            for (int m = 0; m < 4; ++m)
                #pragma unroll
                for (int n = 0; n < 4; ++n)
                    acc[m][n] = __builtin_amdgcn_mfma_f32_16x16x32_bf16(af[m], bfr[n], acc[m][n], 0, 0, 0);
        }

        __syncthreads();
    }

    #pragma unroll
    for (int m = 0; m < 4; ++m) {
        #pragma unroll
        for (int n = 0; n < 4; ++n) {
            const int col = n0 + wc * 64 + n * 16 + lr;
            const float bv = bias[col];
            #pragma unroll
            for (int r = 0; r < 4; ++r) {
                const int row = m0 + wr * 64 + m * 16 + lg * 4 + r;
                Cb[(size_t)row * DDIM + col] = __hip_bfloat16_raw{f2bf(acc[m][n][r] + bv)};
            }
        }
    }
}

// ---------------- G2: out = hidden @ W_heads[idx] + b_heads[idx] ----------------
// Phased deep pipeline (T3+T4+T5 port of the m201 schedule):
// BM=256 BN=128 BK=64, 512 threads (8 waves, 4x2 grid of 64x64 wave tiles),
// FULL double-buffer: 2x(32KB A + 16KB B) = 96 KB dynamic LDS, 1 block/CU.
// Two phases per K-tile, each: {8 ds_read (ks half) | stage-issue cluster} ->
//   SBAR -> lgkmcnt(0)+sched_barrier(0) -> setprio(1) 16 MFMA setprio(0) -> SBAR.
// Stage split: ph1 issues 2 gll (A half 0); ph2 issues 2 gll (A half 1) +
//   WRITEB(next B, consumes br regs) + LOADB(kt+2, 8 loads fly across next tile).
// ONE counted vmcnt(8) per K-tile (after ph2 MFMA, before flip barrier):
//   outstanding = 4 gll + 8 B-loads -> drains exactly the A-DMA (T4: never 0).
// All cluster boundaries SCHED0-pinned so the static vmcnt count is exact (R4 lesson).
// Layouts (R5/R7-validated, conflict-free): A linear + src-preswizzle kbyte^=(row&7)<<4,
// B [n][kk] u32 k-pairs, quad slot kk ^ ((n>>1)&7)<<2.
__global__ __launch_bounds__(512, 2)
void gemm2_k(const __hip_bfloat16* __restrict__ A, const float* __restrict__ Wh,
             const float* __restrict__ bh, float* __restrict__ out,
             const int* __restrict__ dom)
{
    extern __shared__ __align__(16) char smem[];
    __hip_bfloat16* ldsA0 = (__hip_bfloat16*)smem;                    // 32 KB
    __hip_bfloat16* ldsA1 = (__hip_bfloat16*)(smem + 32768);          // 32 KB
    unsigned int*   ldsB0 = (unsigned int*)(smem + 65536);            // 16 KB
    unsigned int*   ldsB1 = (unsigned int*)(smem + 81920);            // 16 KB

    const int tid  = threadIdx.x;
    const int lane = tid & 63;
    const int w    = tid >> 6;      // 0..7
    const int wr   = w >> 1;        // 0..3 -> 64-row stripe
    const int wc   = w & 1;         // 0..1 -> 64-col stripe
    const int lr   = lane & 15;
    const int lg   = lane >> 4;

    // XCD-chunked swizzle; grid = 4000 (%8==0); each XCD streams one example's head.
    const int bid  = blockIdx.x;
    const int q    = gridDim.x >> 3;             // 500
    const int sid  = (bid & 7) * q + (bid >> 3);
    const int mt   = sid & 1;
    const int rest = sid >> 1;
    const int nt   = rest % 250;
    const int ex   = rest / 250;
    const int m0   = ex * SLEN + mt * 256;
    const int n0   = nt * 128;

    const int di  = dom[ex];
    const int hid = (di >= 0 && di < NDOM) ? di : NDOM;
    const float* Bp   = Wh + (size_t)hid * DDIM * (size_t)VDIM;
    const float* bias = bh + (size_t)hid * (size_t)VDIM;

    f32x4 acc[4][4];
    #pragma unroll
    for (int m = 0; m < 4; ++m)
        #pragma unroll
        for (int n = 0; n < 4; ++n)
            acc[m][n] = (f32x4)0.0f;

    // B staging: thread owns 8 k-rows x 2 cols (float2); 512 threads cover 64x128.
    const int nb  = (tid & 63) << 1;     // col base 0..126 (even)
    const int kb  = (tid >> 6) << 3;     // k base 0..56 (8 rows per wave)
    const int qb  = kb >> 1;             // kk-quad slot base (multiple of 4)
    const int bsw = (lane & 7) << 2;     // == ((nb>>1)&7)<<2
    const int bslot = qb ^ bsw;

    float2 br[8];

    #define LOADB(KT) do {                                                         \
        const float* _p = Bp + (size_t)((KT) * 64 + kb) * VDIM + n0 + nb;          \
        _Pragma("unroll")                                                          \
        for (int j = 0; j < 8; ++j) br[j] = *(const float2*)(_p + (size_t)j * VDIM); \
    } while (0)

    #define WRITEB(LB) do {                                                        \
        uint4 w0, w1;                                                              \
        w0.x = pack2(br[0].x, br[1].x); w0.y = pack2(br[2].x, br[3].x);            \
        w0.z = pack2(br[4].x, br[5].x); w0.w = pack2(br[6].x, br[7].x);            \
        w1.x = pack2(br[0].y, br[1].y); w1.y = pack2(br[2].y, br[3].y);            \
        w1.z = pack2(br[4].y, br[5].y); w1.w = pack2(br[6].y, br[7].y);            \
        *(uint4*)&(LB)[nb * 32 + bslot]       = w0;                                \
        *(uint4*)&(LB)[(nb + 1) * 32 + bslot] = w1;                                \
    } while (0)

    // Half-stage of A: H=0 -> i in {0,1}, H=1 -> i in {2,3} (2 gll each)
    #define STAGEA_H(LA, KT, H) do {                                               \
        _Pragma("unroll")                                                          \
        for (int i = 2*(H); i < 2*(H) + 2; ++i) {                                  \
            const int base_e = (i * 8 + w) * 512;                                  \
            const int flat   = base_e + lane * 8;                                  \
            const int row    = flat >> 6;                                          \
            const int kbyte  = (flat & 63) * 2;                                    \
            const int srck   = (kbyte ^ ((row & 7) << 4)) >> 1;                    \
            const __hip_bfloat16* src = A + (size_t)(m0 + row) * DDIM + (KT) * 64 + srck; \
            __builtin_amdgcn_global_load_lds(                                      \
                (const __attribute__((address_space(1))) unsigned int*)src,        \
                (__attribute__((address_space(3))) unsigned int*)((LA) + base_e),  \
                16, 0, 0);                                                         \
        }                                                                          \
    } while (0)

    #define READ_FRAGS(AF, BF, LA, LB, KS) do {                                    \
        _Pragma("unroll")                                                          \
        for (int m = 0; m < 4; ++m) {                                              \
            const int row = wr * 64 + m * 16 + lr;                                 \
            const int kby = (KS) * 64 + lg * 16;                                   \
            const int eff = kby ^ ((row & 7) << 4);                                \
            AF[m] = *(const bf16x8*)&(LA)[row * 64 + (eff >> 1)];                  \
        }                                                                          \
        _Pragma("unroll")                                                          \
        for (int n = 0; n < 4; ++n) {                                              \
            const int col  = wc * 64 + n * 16 + lr;                                \
            const int kkb  = (KS) * 16 + lg * 4;                                   \
            const int slot = kkb ^ (((col >> 1) & 7) << 2);                        \
            BF[n] = *(const bf16x8*)&(LB)[col * 32 + slot];                        \
        }                                                                          \
    } while (0)

    #define MFMA16(AF, BF) do {                                                    \
        _Pragma("unroll")                                                          \
        for (int m = 0; m < 4; ++m)                                                \
            _Pragma("unroll")                                                      \
            for (int n = 0; n < 4; ++n)                                            \
                acc[m][n] = __builtin_amdgcn_mfma_f32_16x16x32_bf16(AF[m], BF[n], acc[m][n], 0, 0, 0); \
    } while (0)

    // ---- prologue: fill buf0, leave B(1) loads in flight ----
    LOADB(0);
    SCHED0();
    STAGEA_H(ldsA0, 0, 0);
    STAGEA_H(ldsA0, 0, 1);
    SCHED0();
    WRITEB(ldsB0);            // compiler counted-vmcnt drains LOADB(0)'s 8
    SCHED0();
    LOADB(1);
    SCHED0();
    asm volatile("s_waitcnt vmcnt(8) lgkmcnt(0)" ::: "memory");  // drain 4 gll + ds_writes
    SCHED0();
    SBAR();

    // ---- main loop: 2 phases per K-tile ----
    for (int kt = 0; kt < 16; ++kt) {
        __hip_bfloat16* lA  = (kt & 1) ? ldsA1 : ldsA0;
        __hip_bfloat16* lAn = (kt & 1) ? ldsA0 : ldsA1;
        unsigned int*   lB  = (kt & 1) ? ldsB1 : ldsB0;
        unsigned int*   lBn = (kt & 1) ? ldsB0 : ldsB1;

        // ======== phase 1: ks=0 ========
        {
            bf16x8 af[4], bfr[4];
            READ_FRAGS(af, bfr, lA, lB, 0);      // 8 ds_read_b128
            SCHED0();
            if (kt < 15) { STAGEA_H(lAn, kt + 1, 0); SCHED0(); }   // 2 gll
            SBAR();
            asm volatile("s_waitcnt lgkmcnt(0)" ::: "memory");
            SCHED0();                             // rule 18: fence MFMA after lgkm wait
            __builtin_amdgcn_s_setprio(1);
            MFMA16(af, bfr);
            __builtin_amdgcn_s_setprio(0);
            SCHED0();
            SBAR();
        }

        // ======== phase 2: ks=1 ========
        {
            bf16x8 af[4], bfr[4];
            READ_FRAGS(af, bfr, lA, lB, 1);      // 8 ds_read_b128
            SCHED0();
            if (kt < 15) {
                STAGEA_H(lAn, kt + 1, 1);        // 2 gll
                SCHED0();
                WRITEB(lBn);                     // consumes br = B(kt+1); compiler vmcnt
                SCHED0();
            }
            if (kt < 14) { LOADB(kt + 2); SCHED0(); }   // 8 loads fly across next tile
            SBAR();
            asm volatile("s_waitcnt lgkmcnt(0)" ::: "memory");
            SCHED0();
            __builtin_amdgcn_s_setprio(1);
            MFMA16(af, bfr);
            __builtin_amdgcn_s_setprio(0);
            SCHED0();
            if (kt < 14) {
                asm volatile("s_waitcnt vmcnt(8)" ::: "memory");   // drain 4 gll; keep 8 B-loads
            } else if (kt == 14) {
                asm volatile("s_waitcnt vmcnt(0)" ::: "memory");   // no LOADB(16): drain gll fully
            }
            SCHED0();
            if (kt < 15) SBAR();                 // flip barrier: buf[nxt] consistent
        }
    }

    // ---- epilogue ----
    #pragma unroll
    for (int n = 0; n < 4; ++n) {
        const int col = n0 + wc * 64 + n * 16 + lr;
        const float bv = bias[col];
        #pragma unroll
        for (int m = 0; m < 4; ++m) {
            #pragma unroll
            for (int r = 0; r < 4; ++r) {
                const int row = m0 + wr * 64 + m * 16 + lg * 4 + r;
                out[(size_t)row * VDIM + col] = acc[m][n][r] + bv;
            }
        }
    }

    #undef LOADB
    #undef WRITEB
    #undef STAGEA_H
    #undef READ_FRAGS
    #undef MFMA16
}

extern "C" void kernel_launch(void* const* d_in, const int* in_sizes, int n_in,
                              void* d_out, int out_size, void* d_ws, size_t ws_size,
                              hipStream_t stream)
{
    const float* hs  = (const float*)d_in[0];   // [8,512,1024] fp32
    const int*   dom = (const int*)d_in[1];     // [8] int32
    const float* Wb  = (const float*)d_in[2];   // [1024,1024] fp32
    const float* bb  = (const float*)d_in[3];   // [1024] fp32
    const float* Wh  = (const float*)d_in[4];   // [9,1024,32000] fp32
    const float* bh  = (const float*)d_in[5];   // [9,32000] fp32
    float* out = (float*)d_out;                 // [8,512,32000] fp32
    __hip_bfloat16* hidden = (__hip_bfloat16*)d_ws;   // [4096,1024] bf16, 8 MB

    const int M = BCNT * SLEN;  // 4096

    // G1: 256 blocks of 256 threads
    const int g1 = (M / 128) * (DDIM / 128);
    hipLaunchKernelGGL(gemm1_k, dim3(g1), dim3(256), 0, stream, hs, Wb, bb, hidden, M);

    // G2: 8 ex * 2 mt * 250 nt = 4000 blocks of 512 threads, 96 KB dynamic LDS
    const int smem_bytes = 98304;
    static int attr_set = 0;
    if (!attr_set) {  // host-side attribute set, idempotent (R3-validated pattern)
        hipFuncSetAttribute((const void*)gemm2_k, hipFuncAttributeMaxDynamicSharedMemorySize, smem_bytes);
        attr_set = 1;
    }
    const int g2 = BCNT * (SLEN / 256) * (VDIM / 128);
    hipLaunchKernelGGL(gemm2_k, dim3(g2), dim3(512), smem_bytes, stream, hidden, Wh, bh, out, dom);
}